// Round 3
// baseline (115.504 us; speedup 1.0000x reference)
//
#include <hip/hip_runtime.h>

#define IMG_H 1080
#define IMG_W 1920
#define TILE_W 128
#define TILE_H 32
#define SW 134           // TILE_W + 6
#define SH 38            // TILE_H + 6
#define SP 136           // padded LDS row stride (floats); 136*4B = 16B multiple

typedef float f32x4 __attribute__((ext_vector_type(4)));

// Nonzero iff the 16-bit circular mask has 9 consecutive set bits.
__device__ __forceinline__ unsigned det9(unsigned m) {
    unsigned x = m | (m << 16);
    unsigned t = x & (x >> 1);   // run 2
    t &= t >> 2;                 // run 4
    t &= t >> 4;                 // run 8
    t &= x >> 8;                 // run 9
    return t;
}

__global__ __launch_bounds__(256, 2) void fast_score_kernel(const float* __restrict__ img,
                                                            float* __restrict__ out) {
    __shared__ float sm[SH * SP];

    const int n  = blockIdx.z;
    const int x0 = blockIdx.x * TILE_W;
    const int y0 = blockIdx.y * TILE_H;
    const int tid = threadIdx.x;

    const float* in = img + (size_t)n * (IMG_H * IMG_W);
    float* op = out + (size_t)n * (IMG_H * IMG_W);

    // ---- stage tile + halo into LDS (replicate-clamped) ----
    {
        const int lane = tid & 63;
        const int rgrp = tid >> 6;
        for (int r = rgrp; r < SH; r += 4) {
            int gy = y0 - 3 + r;
            gy = min(max(gy, 0), IMG_H - 1);
            const float* rowp = in + (size_t)gy * IMG_W;
            for (int c = lane; c < SW; c += 64) {
                int gx = x0 - 3 + c;
                gx = min(max(gx, 0), IMG_W - 1);
                sm[r * SP + c] = rowp[gx];
            }
        }
    }
    __syncthreads();

    // ---- 4x4 output patch per thread, full 10x12 register window ----
    const int cg = tid & 31;     // 32 col groups * 4 = 128 cols
    const int rg = tid >> 5;     // 8 row groups * 4 = 32 rows
    const int C = cg * 4;
    const int R = rg * 4;

    f32x4 w[10][3];              // 10 rows x 12 cols = 120 floats, pinned in VGPRs
#pragma unroll
    for (int j = 0; j < 10; ++j) {
        const float* sp = &sm[(R + j) * SP + C];
#pragma unroll
        for (int q = 0; q < 3; ++q) {
            w[j][q] = *(const f32x4*)(sp + 4 * q);
            asm volatile("" : "+v"(w[j][q]));   // forbid remat: value must stay in VGPRs
        }
    }

#define WELEM(r_, c_) (w[(r_)][(c_) >> 2][(c_) & 3])

    constexpr int DY[16] = {0, 1, 2, 3, 3, 3, 2, 1, 0, -1, -2, -3, -3, -3, -2, -1};
    constexpr int DX[16] = {-3, -3, -2, -1, 0, 1, 2, 3, 3, 3, 2, 1, 0, -1, -2, -3};

#pragma unroll
    for (int rr = 0; rr < 4; ++rr) {
        float res[4];
#pragma unroll
        for (int cc = 0; cc < 4; ++cc) {
            const float center = WELEM(rr + 3, cc + 3);
            const float hi = center + 20.0f;
            const float lo = center - 20.0f;
            unsigned dark = 0u, bright = 0u;
#pragma unroll
            for (int k = 0; k < 16; ++k) {
                const float t = WELEM(rr + 3 + DY[k], cc + 3 + DX[k]);
                dark   = (dark << 1)   + (t >= hi ? 1u : 0u);
                bright = (bright << 1) + (t <= lo ? 1u : 0u);
            }
            res[cc] = (det9(dark) | det9(bright)) ? 1.0f : 0.0f;
        }
        const int gy = y0 + R + rr;
        if (gy < IMG_H) {
            *(float4*)(op + (size_t)gy * IMG_W + (x0 + C)) =
                make_float4(res[0], res[1], res[2], res[3]);
        }
    }
}

extern "C" void kernel_launch(void* const* d_in, const int* in_sizes, int n_in,
                              void* d_out, int out_size, void* d_ws, size_t ws_size,
                              hipStream_t stream) {
    const float* img = (const float*)d_in[0];
    float* out = (float*)d_out;
    const int n_img = in_sizes[0] / (IMG_H * IMG_W);   // = 4
    dim3 grid((IMG_W + TILE_W - 1) / TILE_W,           // 15
              (IMG_H + TILE_H - 1) / TILE_H,           // 34
              n_img);
    fast_score_kernel<<<grid, 256, 0, stream>>>(img, out);
}